// Round 8
// baseline (521.894 us; speedup 1.0000x reference)
//
#include <hip/hip_runtime.h>
#include <hip/hip_bf16.h>

#define N 8192
#define IN_F 128
#define OUT_F 64
#define LRELU_ALPHA 0.2f

typedef __attribute__((ext_vector_type(8))) short short8;
typedef __attribute__((ext_vector_type(4))) float float4v;

__device__ __forceinline__ unsigned short bf16_bits(float x) {
  unsigned u = __builtin_bit_cast(unsigned, x);
  u += 0x7fffu + ((u >> 16) & 1u);  // round-to-nearest-even
  return (unsigned short)(u >> 16);
}

// prep: Wh = h@W (fp32), s1 = Wh@a1, s2 = Wh@a2, whT bf16 [64][8192]
__global__ __launch_bounds__(256) void prep_kernel(
    const float* __restrict__ h, const float* __restrict__ W,
    const float* __restrict__ a, float* __restrict__ s1,
    float* __restrict__ s2, unsigned short* __restrict__ whT) {
  const int tid = threadIdx.x;
  const int row = blockIdx.x * 4 + (tid >> 6);
  const int k = tid & 63;
  const float* hr = h + row * IN_F;
  float acc = 0.f;
#pragma unroll 8
  for (int c = 0; c < IN_F; ++c) acc = fmaf(hr[c], W[c * OUT_F + k], acc);
  whT[(long)k * N + row] = bf16_bits(acc);
  float p1 = acc * a[k];
  float p2 = acc * a[OUT_F + k];
#pragma unroll
  for (int off = 32; off > 0; off >>= 1) {
    p1 += __shfl_xor(p1, off);
    p2 += __shfl_xor(p2, off);
  }
  if (k == 0) { s1[row] = p1; s2[row] = p2; }
}

// repack whT [64][8192] -> B-fragment order: whF[(c32*256 + tt*64 + lane)*8]
// lane=(quad,r16): holds Wh[node=c32*32+quad*8+j][dim=tt*16+r16], j=0..7.
__global__ __launch_bounds__(256) void repack_kernel(
    const unsigned short* __restrict__ whT, unsigned short* __restrict__ whF) {
  const int f = blockIdx.x * 256 + threadIdx.x;  // 0..65535 fragments
  const int lane = f & 63, tt = (f >> 6) & 3, c = f >> 8;
  const int r16 = lane & 15, quad = lane >> 4;
  const short8 v = *(const short8*)(whT + (long)(tt * 16 + r16) * N + c * 32 + quad * 8);
  *(short8*)(whF + (long)f * 8) = v;
}

// Pass 1 — pure streaming, NO LDS / NO barriers / NO shuffles.
// Grid (512 rowtiles, 4 col-chunks) x 256 thr. Wave w owns 16 rows x 512-col
// strip; per row: 2KB contiguous adj read (2 x 1KB instructions), p = exp(e)
// (no online softmax; masked -> 0), one 16B A-frag-granule write per lane into
// pfrag, densely covering a 16KB window over the 16-row loop (full-line L2
// writeback). pfrag layout == MFMA A-fragment order consumed by pv_kernel:
//   pfrag[((rt*256 + c)*64 + quad*16 + r16)*8 + i] = p(rt*16+r16, c*32+quad*8+i)
__global__ __launch_bounds__(256) void pscore_kernel(
    const int* __restrict__ adj, const float* __restrict__ s1,
    const float* __restrict__ s2, unsigned short* __restrict__ pfrag) {
  const int tid = threadIdx.x;
  const int w = tid >> 6, L = tid & 63;
  const int rt = blockIdx.x, cs = blockIdx.y;
  const int row0 = rt * 16;
  const int j0 = cs * 2048 + w * 512 + L * 8;  // this lane's 8 columns
  const float4 sv0 = *(const float4*)(s2 + j0);
  const float4 sv1 = *(const float4*)(s2 + j0 + 4);
  const int c = j0 >> 5, quad = (j0 >> 3) & 3;
  unsigned short* dst = pfrag + ((long)(rt * 256 + c) * 64 + quad * 16) * 8;
#pragma unroll
  for (int r = 0; r < 16; ++r) {
    const int4* ap = (const int4*)(adj + (long)(row0 + r) * N + j0);
    const int4 a0 = ap[0], a1 = ap[1];
    const float s1w = s1[row0 + r];  // wave-uniform scalar load
    float e[8];
    e[0] = s1w + sv0.x; e[1] = s1w + sv0.y; e[2] = s1w + sv0.z; e[3] = s1w + sv0.w;
    e[4] = s1w + sv1.x; e[5] = s1w + sv1.y; e[6] = s1w + sv1.z; e[7] = s1w + sv1.w;
    const int am[8] = {a0.x, a0.y, a0.z, a0.w, a1.x, a1.y, a1.z, a1.w};
    short8 pk;
#pragma unroll
    for (int i = 0; i < 8; ++i) {
      float t = fmaxf(e[i], LRELU_ALPHA * e[i]);  // leaky-relu, alpha<1
      const float p = am[i] > 0 ? __expf(t) : 0.f;
      pk[i] = (short)bf16_bits(p);
    }
    *(short8*)(dst + r * 8) = pk;
  }
}

// Pass 2 — thin-N GEMM: out = softmax-normalize(P) @ Wh, elu.
// Grid 512 (one rowtile) x 512 thr (8 waves, K-split 32 chunks each).
// A-frags stream SEQUENTIALLY from pfrag (16B/lane contiguous); B-frags from
// L2-resident whF; denominator via 5th MFMA against ones. One barrier total.
__global__ __launch_bounds__(512) void pv_kernel(
    const unsigned short* __restrict__ pfrag,
    const unsigned short* __restrict__ whF, float* __restrict__ out) {
  __shared__ float lds_acc[8][16][65];  // +1 pad
  __shared__ float lds_l[8][16];
  const int tid = threadIdx.x;
  const int w = tid >> 6, L = tid & 63;
  const int r16 = L & 15, quad = L >> 4;
  const int rt = blockIdx.x, row0 = rt * 16;

  float4v acc0 = {0.f, 0.f, 0.f, 0.f};
  float4v acc1 = {0.f, 0.f, 0.f, 0.f};
  float4v acc2 = {0.f, 0.f, 0.f, 0.f};
  float4v acc3 = {0.f, 0.f, 0.f, 0.f};
  float4v accD = {0.f, 0.f, 0.f, 0.f};
  const short ONE = (short)0x3F80;  // bf16 1.0
  const short8 ones = {ONE, ONE, ONE, ONE, ONE, ONE, ONE, ONE};

  const unsigned short* ap = pfrag + ((long)(rt * 256 + w * 32) * 64 + L) * 8;
  const unsigned short* bp0 = whF + ((long)(w * 32) * 256 + L) * 8;
#pragma unroll 4
  for (int cc = 0; cc < 32; ++cc) {
    const short8 afrag = *(const short8*)(ap + (long)cc * 512);
    const unsigned short* bp = bp0 + (long)cc * 2048;
    const short8 b0 = *(const short8*)(bp);
    const short8 b1 = *(const short8*)(bp + 512);
    const short8 b2 = *(const short8*)(bp + 1024);
    const short8 b3 = *(const short8*)(bp + 1536);
    acc0 = __builtin_amdgcn_mfma_f32_16x16x32_bf16(afrag, b0, acc0, 0, 0, 0);
    acc1 = __builtin_amdgcn_mfma_f32_16x16x32_bf16(afrag, b1, acc1, 0, 0, 0);
    acc2 = __builtin_amdgcn_mfma_f32_16x16x32_bf16(afrag, b2, acc2, 0, 0, 0);
    acc3 = __builtin_amdgcn_mfma_f32_16x16x32_bf16(afrag, b3, acc3, 0, 0, 0);
    accD = __builtin_amdgcn_mfma_f32_16x16x32_bf16(afrag, ones, accD, 0, 0, 0);
  }

#pragma unroll
  for (int reg = 0; reg < 4; ++reg) {
    const int r = quad * 4 + reg;  // C-layout: row=quad*4+reg, col=r16
    lds_acc[w][r][0 * 16 + r16] = acc0[reg];
    lds_acc[w][r][1 * 16 + r16] = acc1[reg];
    lds_acc[w][r][2 * 16 + r16] = acc2[reg];
    lds_acc[w][r][3 * 16 + r16] = acc3[reg];
    if (r16 == 0) lds_l[w][r] = accD[reg];  // all cols of accD equal
  }
  __syncthreads();

  for (int o = tid; o < 16 * 64; o += 512) {
    const int r = o >> 6, k = o & 63;
    float S = 0.f, Lx = 0.f;
#pragma unroll
    for (int s = 0; s < 8; ++s) {
      S += lds_acc[s][r][k];
      Lx += lds_l[s][r];
    }
    const float v = S / Lx;
    out[(long)(row0 + r) * OUT_F + k] = v > 0.f ? v : expm1f(v);
  }
}

extern "C" void kernel_launch(void* const* d_in, const int* in_sizes, int n_in,
                              void* d_out, int out_size, void* d_ws, size_t ws_size,
                              hipStream_t stream) {
  const float* h = (const float*)d_in[0];
  const int* adj = (const int*)d_in[1];
  const float* W = (const float*)d_in[2];
  const float* a = (const float*)d_in[3];
  float* out = (float*)d_out;

  // ws: s1[8192] | s2[8192] | whT[64*8192] bf16 | whF[64*8192] bf16 |
  //     pfrag[8192*8192] bf16 (128MB)
  float* s1 = (float*)d_ws;
  float* s2 = s1 + N;
  unsigned short* whT = (unsigned short*)(s2 + N);
  unsigned short* whF = whT + (long)OUT_F * N;
  unsigned short* pfrag = whF + (long)OUT_F * N;

  prep_kernel<<<N / 4, 256, 0, stream>>>(h, W, a, s1, s2, whT);
  repack_kernel<<<N * OUT_F / 8 / 256, 256, 0, stream>>>(whT, whF);
  pscore_kernel<<<dim3(N / 16, 4), 256, 0, stream>>>(adj, s1, s2, pfrag);
  pv_kernel<<<N / 16, 512, 0, stream>>>(pfrag, whF, out);
}

// Round 10
// 416.838 us; speedup vs baseline: 1.2520x; 1.2520x over previous
//
#include <hip/hip_runtime.h>
#include <hip/hip_bf16.h>

#define N 8192
#define IN_F 128
#define OUT_F 64
#define LRELU_ALPHA 0.2f
#define SPLIT 4    // column splits
#define RPB 64     // rows per block
#define CPB 2048   // cols per block = N/SPLIT
#define WIN 512    // cols per window
#define NWIN 4     // CPB/WIN
#define TSTR 129   // granules per p-tile row (128 + 1 pad -> conflict-free)

typedef __attribute__((ext_vector_type(8))) short short8;
typedef __attribute__((ext_vector_type(4))) short short4v;
typedef __attribute__((ext_vector_type(4))) float float4v;
typedef __attribute__((ext_vector_type(4))) unsigned short ushortx4;

__device__ __forceinline__ unsigned short bf16_bits(float x) {
  unsigned u = __builtin_bit_cast(unsigned, x);
  u += 0x7fffu + ((u >> 16) & 1u);  // round-to-nearest-even
  return (unsigned short)(u >> 16);
}

// prep: Wh = h@W (fp32), s1 = Wh@a1, s2 = Wh@a2, whT bf16 [64][8192]
__global__ __launch_bounds__(256) void prep_kernel(
    const float* __restrict__ h, const float* __restrict__ W,
    const float* __restrict__ a, float* __restrict__ s1,
    float* __restrict__ s2, unsigned short* __restrict__ whT) {
  const int tid = threadIdx.x;
  const int row = blockIdx.x * 4 + (tid >> 6);
  const int k = tid & 63;
  const float* hr = h + row * IN_F;
  float acc = 0.f;
#pragma unroll 8
  for (int c = 0; c < IN_F; ++c) acc = fmaf(hr[c], W[c * OUT_F + k], acc);
  whT[(long)k * N + row] = bf16_bits(acc);
  float p1 = acc * a[k];
  float p2 = acc * a[OUT_F + k];
#pragma unroll
  for (int off = 32; off > 0; off >>= 1) {
    p1 += __shfl_xor(p1, off);
    p2 += __shfl_xor(p2, off);
  }
  if (k == 0) { s1[row] = p1; s2[row] = p2; }
}

// repack whT [64][8192] -> B-fragment order: whF[(c32*256 + tt*64 + lane)*8]
// lane=(quad,r16): holds Wh[node=c32*32+quad*8+j][dim=tt*16+r16], j=0..7.
__global__ __launch_bounds__(256) void repack_kernel(
    const unsigned short* __restrict__ whT, unsigned short* __restrict__ whF) {
  const int f = blockIdx.x * 256 + threadIdx.x;  // 0..65535 fragments
  const int lane = f & 63, tt = (f >> 6) & 3, c = f >> 8;
  const int r16 = lane & 15, quad = lane >> 4;
  const short8 v = *(const short8*)(whT + (long)(tt * 16 + r16) * N + c * 32 + quad * 8);
  *(short8*)(whF + (long)f * 8) = v;
}

// compute 4 p's, write one 8B granule, return their sum
__device__ __forceinline__ float p_half(unsigned short* dst, int4 av,
                                        float4 s2v, float s1w) {
  float e0 = s1w + s2v.x; e0 = fmaxf(e0, LRELU_ALPHA * e0);
  float e1 = s1w + s2v.y; e1 = fmaxf(e1, LRELU_ALPHA * e1);
  float e2 = s1w + s2v.z; e2 = fmaxf(e2, LRELU_ALPHA * e2);
  float e3 = s1w + s2v.w; e3 = fmaxf(e3, LRELU_ALPHA * e3);
  const float p0 = av.x > 0 ? __expf(e0) : 0.f;
  const float p1 = av.y > 0 ? __expf(e1) : 0.f;
  const float p2 = av.z > 0 ? __expf(e2) : 0.f;
  const float p3 = av.w > 0 ? __expf(e3) : 0.f;
  ushortx4 pk = {bf16_bits(p0), bf16_bits(p1), bf16_bits(p2), bf16_bits(p3)};
  *(ushortx4*)dst = pk;
  return (p0 + p1) + (p2 + p3);
}

// Fused GAT partial: grid (128 rowtiles, 4 colsplits) x 512 thr (8 waves).
// 64 rows x 2048 cols per block. s2 staged in LDS once (kills the 512MB s2
// re-read); whF chunk read ONCE per block (wave w owns chunks {w, w+8} for
// all 4 row-tiles -> whF traffic 8192/RPB = 128MB total). p-tile single-
// buffered in granule layout (stride TSTR=129 -> b64-floor banks for both
// producer and consumer). Two __syncthreads per 512-col window (8 total).
// Denominator = per-lane row sums (producer owns rows) + end shuffle.
__global__ __launch_bounds__(512, 4) void gat_kernel(
    const int* __restrict__ adj, const float* __restrict__ s1,
    const float* __restrict__ s2, const unsigned short* __restrict__ whF,
    float* __restrict__ pacc, float* __restrict__ pl) {
  __shared__ __align__(16) unsigned short ptile[RPB * TSTR * 4];  // 66048B
  __shared__ __align__(16) float s2l[CPB];                        // 8192B
  const int tid = threadIdx.x;
  const int w = tid >> 6, L = tid & 63;
  const int r16 = L & 15, quad = L >> 4;
  const int rb = blockIdx.x, cs = blockIdx.y;
  const int row0 = rb * RPB;
  const int colbase = cs * CPB;

  *(float4*)(s2l + tid * 4) = *(const float4*)(s2 + colbase + tid * 4);

  float s1r[8];  // wave-uniform -> scalar loads
#pragma unroll
  for (int j = 0; j < 8; ++j) s1r[j] = s1[row0 + w * 8 + j];

  float lsum[8] = {0.f, 0.f, 0.f, 0.f, 0.f, 0.f, 0.f, 0.f};
  float4v acc[4][4];
#pragma unroll
  for (int rt = 0; rt < 4; ++rt)
#pragma unroll
    for (int dt = 0; dt < 4; ++dt) acc[rt][dt] = (float4v){0.f, 0.f, 0.f, 0.f};

  __syncthreads();  // s2l ready

  for (int it = 0; it < NWIN; ++it) {
    // ---- produce: rows w*8..w*8+7, cols it*512 + {L*4, 256+L*4} ----
    const int c0 = it * WIN + L * 4;
    const float4 sva = *(const float4*)(s2l + c0);
    const float4 svb = *(const float4*)(s2l + c0 + 256);
#pragma unroll
    for (int half = 0; half < 2; ++half) {
      int4 ja[4], jb[4];
#pragma unroll
      for (int j2 = 0; j2 < 4; ++j2) {
        const int r = half * 4 + j2;
        const long arow = (long)(row0 + w * 8 + r) * N + colbase + c0;
        ja[j2] = *(const int4*)(adj + arow);
        jb[j2] = *(const int4*)(adj + arow + 256);
      }
#pragma unroll
      for (int j2 = 0; j2 < 4; ++j2) {
        const int r = half * 4 + j2;
        unsigned short* rowp = ptile + (w * 8 + r) * TSTR * 4;
        lsum[r] += p_half(rowp + L * 4, ja[j2], sva, s1r[r]);
        lsum[r] += p_half(rowp + (64 + L) * 4, jb[j2], svb, s1r[r]);
      }
    }
    __syncthreads();  // p-tile published
    // ---- consume: wave w owns chunks {w, w+8}, all 4 row-tiles ----
#pragma unroll
    for (int ci = 0; ci < 2; ++ci) {
      const int c = w + ci * 8;
      const unsigned short* bp =
          whF + ((long)(cs * 64 + it * 16 + c) * 256 + L) * 8;
      const short8 b0 = *(const short8*)(bp);
      const short8 b1 = *(const short8*)(bp + 512);
      const short8 b2 = *(const short8*)(bp + 1024);
      const short8 b3 = *(const short8*)(bp + 1536);
#pragma unroll
      for (int rt = 0; rt < 4; ++rt) {
        const int g = (rt * 16 + r16) * TSTR + c * 8 + quad * 2;
        const short4v alo = *(const short4v*)(ptile + g * 4);
        const short4v ahi = *(const short4v*)(ptile + g * 4 + 4);
        const short8 afrag =
            __builtin_shufflevector(alo, ahi, 0, 1, 2, 3, 4, 5, 6, 7);
        acc[rt][0] = __builtin_amdgcn_mfma_f32_16x16x32_bf16(afrag, b0, acc[rt][0], 0, 0, 0);
        acc[rt][1] = __builtin_amdgcn_mfma_f32_16x16x32_bf16(afrag, b1, acc[rt][1], 0, 0, 0);
        acc[rt][2] = __builtin_amdgcn_mfma_f32_16x16x32_bf16(afrag, b2, acc[rt][2], 0, 0, 0);
        acc[rt][3] = __builtin_amdgcn_mfma_f32_16x16x32_bf16(afrag, b3, acc[rt][3], 0, 0, 0);
      }
    }
    __syncthreads();  // reads drained before next window overwrites p-tile
  }

  // denominators: reduce each of 8 row-sums across the wave
#pragma unroll
  for (int j = 0; j < 8; ++j) {
    float v = lsum[j];
#pragma unroll
    for (int off = 1; off < 64; off <<= 1) v += __shfl_xor(v, off);
    if (L == 0) pl[(long)cs * N + row0 + w * 8 + j] = v;
  }

  // K-merge across 8 waves in LDS (4 slots x 4096 floats = 64KB <= ptile)
  float* M = (float*)ptile;
  if (w >= 4) {
    float* S = M + (w - 4) * 4096;
#pragma unroll
    for (int rt = 0; rt < 4; ++rt)
#pragma unroll
      for (int dt = 0; dt < 4; ++dt)
#pragma unroll
        for (int reg = 0; reg < 4; ++reg)
          S[(rt * 16 + quad * 4 + reg) * 64 + dt * 16 + r16] = acc[rt][dt][reg];
  }
  __syncthreads();
  if (w < 4) {
    float* S = M + w * 4096;
#pragma unroll
    for (int rt = 0; rt < 4; ++rt)
#pragma unroll
      for (int dt = 0; dt < 4; ++dt)
#pragma unroll
        for (int reg = 0; reg < 4; ++reg)
          S[(rt * 16 + quad * 4 + reg) * 64 + dt * 16 + r16] += acc[rt][dt][reg];
  }
  __syncthreads();
#pragma unroll
  for (int o = tid; o < 1024; o += 512) {
    const int r = o >> 4, k4 = (o & 15) * 4;
    float4 v0 = *(const float4*)(M + 0 * 4096 + r * 64 + k4);
    const float4 v1 = *(const float4*)(M + 1 * 4096 + r * 64 + k4);
    const float4 v2 = *(const float4*)(M + 2 * 4096 + r * 64 + k4);
    const float4 v3 = *(const float4*)(M + 3 * 4096 + r * 64 + k4);
    v0.x += v1.x + v2.x + v3.x;
    v0.y += v1.y + v2.y + v3.y;
    v0.z += v1.z + v2.z + v3.z;
    v0.w += v1.w + v2.w + v3.w;
    *(float4*)(pacc + ((long)cs * N + row0 + r) * OUT_F + k4) = v0;
  }
}

// merge SPLIT partials, normalize, elu
__global__ __launch_bounds__(256) void merge_kernel(
    const float* __restrict__ pacc, const float* __restrict__ pl,
    float* __restrict__ out) {
  const int idx = blockIdx.x * 256 + threadIdx.x;  // 0..131071
  const int r = idx >> 4;
  const int k4 = (idx & 15) * 4;
  float4 S = {0.f, 0.f, 0.f, 0.f};
  float Lx = 0.f;
#pragma unroll
  for (int c = 0; c < SPLIT; ++c) {
    const float4 p = *(const float4*)(pacc + ((long)c * N + r) * OUT_F + k4);
    S.x += p.x; S.y += p.y; S.z += p.z; S.w += p.w;
    Lx += pl[(long)c * N + r];
  }
  const float inv = 1.f / Lx;
  float v[4] = {S.x * inv, S.y * inv, S.z * inv, S.w * inv};
  float4 o;
  o.x = v[0] > 0.f ? v[0] : expm1f(v[0]);
  o.y = v[1] > 0.f ? v[1] : expm1f(v[1]);
  o.z = v[2] > 0.f ? v[2] : expm1f(v[2]);
  o.w = v[3] > 0.f ? v[3] : expm1f(v[3]);
  *(float4*)(out + (long)r * OUT_F + k4) = o;
}

extern "C" void kernel_launch(void* const* d_in, const int* in_sizes, int n_in,
                              void* d_out, int out_size, void* d_ws, size_t ws_size,
                              hipStream_t stream) {
  const float* h = (const float*)d_in[0];
  const int* adj = (const int*)d_in[1];
  const float* W = (const float*)d_in[2];
  const float* a = (const float*)d_in[3];
  float* out = (float*)d_out;

  // ws: s1[8192] | s2[8192] | whT[64*8192] bf16 | whF[64*8192] bf16 |
  //     pacc[SPLIT][8192][64] f32 (8MB) | pl[SPLIT][8192] f32
  float* s1 = (float*)d_ws;
  float* s2 = s1 + N;
  unsigned short* whT = (unsigned short*)(s2 + N);
  unsigned short* whF = whT + (long)OUT_F * N;
  float* pacc = (float*)(whF + (long)OUT_F * N);
  float* pl = pacc + (long)SPLIT * N * OUT_F;

  prep_kernel<<<N / 4, 256, 0, stream>>>(h, W, a, s1, s2, whT);
  repack_kernel<<<N * OUT_F / 8 / 256, 256, 0, stream>>>(whT, whF);
  gat_kernel<<<dim3(N / RPB, SPLIT), 512, 0, stream>>>(adj, s1, s2, whF, pacc, pl);
  merge_kernel<<<N * OUT_F / 4 / 256, 256, 0, stream>>>(pacc, pl, out);
}